// Round 19
// baseline (714.773 us; speedup 1.0000x reference)
//
#include <hip/hip_runtime.h>
#include <hip/hip_bf16.h>

#define N_NODES 50000
#define NE      800000
#define NBLK_SCAN 196   // ceil(50000/256)

typedef __attribute__((ext_vector_type(4))) float f32x4;
typedef __attribute__((ext_vector_type(8))) short s16x8;
typedef __attribute__((ext_vector_type(8))) unsigned short u16x8;

__device__ __forceinline__ float bf2f(unsigned short u) {
    union { unsigned int i; float f; } v; v.i = ((unsigned int)u) << 16; return v.f;
}
__device__ __forceinline__ unsigned short f2bf(float f) {
    union { unsigned int i; float f; } v; v.f = f;
    unsigned int x = v.i;
    return (unsigned short)((x + 0x7fffu + ((x >> 16) & 1u)) >> 16);  // RNE
}

// ---------------- weights (both) -> bf16 transposed, one dispatch ----------------
__global__ void k_wt2(const float* __restrict__ W1, const float* __restrict__ W2,
                      unsigned short* __restrict__ Wt1, unsigned short* __restrict__ Wt2)
{
    int b = blockIdx.x;
    if (b < 768) {
        int idx = b * 256 + threadIdx.x;          // Wt1 flat = j*768 + k
        int j = idx / 768, k = idx - j * 768;
        Wt1[idx] = f2bf(W1[(size_t)k * 256 + j]);
    } else {
        int idx = (b - 768) * 256 + threadIdx.x;  // Wt2 flat = j*512 + k
        int j = idx >> 9, k = idx & 511;
        Wt2[idx] = f2bf(W2[(size_t)k * 256 + j]);
    }
}

// ---------------- S fp32 [256][256] -> St bf16 transposed ----------------
__global__ void k_st(const float* __restrict__ S, unsigned short* __restrict__ St)
{
    int k = blockIdx.x, j = threadIdx.x;
    St[j * 256 + k] = f2bf(S[k * 256 + j]);
}

// ---------------- both GEMMs in ONE dispatch; 128x256 tile, BK=64, 2x4 waves ----------------
__global__ __launch_bounds__(512) void k_gemm2(
    const float* __restrict__ X1, const float* __restrict__ X2,
    const unsigned short* __restrict__ Wt1, const unsigned short* __restrict__ Wt2,
    const float* __restrict__ b1f, const float* __restrict__ b2f,
    float* __restrict__ o1, float* __restrict__ o2,
    unsigned short* __restrict__ z1, unsigned short* __restrict__ z2, int M)
{
    __shared__ unsigned short Alds[128][72];
    __shared__ unsigned short Blds[256][72];
    __shared__ float part[4][136];
    const int zz = blockIdx.z;
    const float* X = zz ? X2 : X1;
    const unsigned short* Wt = zz ? Wt2 : Wt1;
    const float* bias = zz ? b2f : b1f;
    float* out = zz ? o2 : o1;
    unsigned short* Zb = zz ? z2 : z1;
    const int K = zz ? 512 : 768;

    const int tid = threadIdx.x;
    const int m0 = blockIdx.x * 128;
    const int wave = tid >> 6, lane = tid & 63;
    const int wr = wave >> 2, wc = wave & 3;
    const int l15 = lane & 15, lg = lane >> 4;

    f32x4 acc[4][4];
    for (int a = 0; a < 4; ++a) for (int b = 0; b < 4; ++b) acc[a][b] = (f32x4)0.0f;

    for (int k0 = 0; k0 < K; k0 += 64) {
        for (int p = 0; p < 4; ++p) {
            int idx = tid + p * 512;          // 2048 float4 = 128 rows x 16
            int r = idx >> 4, c4 = idx & 15;
            int row = m0 + r;
            float4 v = make_float4(0.f, 0.f, 0.f, 0.f);
            if (row < M) v = *(const float4*)(X + (size_t)row * K + k0 + c4 * 4);
            ushort4 pk;
            pk.x = f2bf(v.x); pk.y = f2bf(v.y); pk.z = f2bf(v.z); pk.w = f2bf(v.w);
            *(ushort4*)&Alds[r][c4 * 4] = pk;
        }
        for (int p = 0; p < 4; ++p) {
            int idx = tid + p * 512;          // 2048 u16x8
            int j = idx >> 3, k8 = idx & 7;
            *(u16x8*)&Blds[j][k8 * 8] = *(const u16x8*)(Wt + (size_t)j * K + k0 + k8 * 8);
        }
        __syncthreads();
        for (int kk = 0; kk < 2; ++kk) {
            s16x8 af[4], bfr[4];
            for (int mt = 0; mt < 4; ++mt)
                af[mt] = *(const s16x8*)&Alds[wr * 64 + mt * 16 + l15][kk * 32 + lg * 8];
            for (int nt = 0; nt < 4; ++nt)
                bfr[nt] = *(const s16x8*)&Blds[wc * 64 + nt * 16 + l15][kk * 32 + lg * 8];
            for (int mt = 0; mt < 4; ++mt)
                for (int nt = 0; nt < 4; ++nt)
                    acc[mt][nt] = __builtin_amdgcn_mfma_f32_16x16x32_bf16(af[mt], bfr[nt], acc[mt][nt], 0, 0, 0);
        }
        __syncthreads();
    }

    for (int mt = 0; mt < 4; ++mt) {
        for (int nt = 0; nt < 4; ++nt) {
            float bb = bias[wc * 64 + nt * 16 + l15];
            for (int r = 0; r < 4; ++r) acc[mt][nt][r] += bb;
        }
        for (int r = 0; r < 4; ++r) {
            float p = 0.f;
            for (int nt = 0; nt < 4; ++nt) p += acc[mt][nt][r] * acc[mt][nt][r];
            p += __shfl_xor(p, 1); p += __shfl_xor(p, 2);
            p += __shfl_xor(p, 4); p += __shfl_xor(p, 8);
            if (l15 == 0) part[wc][wr * 64 + mt * 16 + lg * 4 + r] = p;
        }
    }
    __syncthreads();
    for (int mt = 0; mt < 4; ++mt) {
        for (int r = 0; r < 4; ++r) {
            int rl = wr * 64 + mt * 16 + lg * 4 + r;
            float s = part[0][rl] + part[1][rl] + part[2][rl] + part[3][rl];
            float inv = 1.0f / fmaxf(sqrtf(s), 1e-12f);
            int row = m0 + rl;
            if (row < M) {
                for (int nt = 0; nt < 4; ++nt) {
                    float v = acc[mt][nt][r] * inv;
                    size_t o = (size_t)row * 256 + wc * 64 + nt * 16 + l15;
                    out[o] = v;
                    Zb[o] = f2bf(v);
                }
            }
        }
    }
}

// ---------------- Gram single-pass: wave owns 32 G-rows; Z read ONCE per matrix ----------------
// grid (196 m-groups of 4 chunks... -> 196 groups of 8? see host: (196,2) with 4 chunks) 
// Here: blockIdx.x in [0,196), each covers 4 chunks of 64 rows; blockIdx.y = matrix.
__global__ __launch_bounds__(512) void k_gram_mfma(
    const unsigned short* __restrict__ Zb1, const unsigned short* __restrict__ Zb2,
    float* __restrict__ G1, float* __restrict__ G2, int M)
{
    __shared__ unsigned short Zt[256][72];
    const unsigned short* Z = blockIdx.y ? Zb2 : Zb1;
    float* G = blockIdx.y ? G2 : G1;
    const int tid = threadIdx.x;
    const int wave = tid >> 6, lane = tid & 63;
    const int l15 = lane & 15, lg = lane >> 4;
    const int TC = (M + 63) >> 6;                 // 782
    const int c0 = blockIdx.x * 4;
    const int c1 = min(c0 + 4, TC);

    const int ja0 = wave * 32 + l15;
    const int ja1 = wave * 32 + 16 + l15;
    const int sa0 = ((ja0 >> 2) & 7) << 3;
    const int sa1 = ((ja1 >> 2) & 7) << 3;

    f32x4 acc[2][16];
    for (int a = 0; a < 2; ++a) for (int b = 0; b < 16; ++b) acc[a][b] = (f32x4)0.0f;

    for (int ch = c0; ch < c1; ++ch) {
        int base = ch * 64;
        __syncthreads();
        for (int p = 0; p < 4; ++p) {
            int idx = tid + p * 512;              // 2048 u16x8 = 64 m x 32 c8
            int m = idx >> 5, c8 = idx & 31;
            int row = base + m;
            u16x8 v = (u16x8)0;
            if (row < M) v = *(const u16x8*)(Z + (size_t)row * 256 + c8 * 8);
            for (int q = 0; q < 8; ++q) {
                int f = c8 * 8 + q;
                int cs = m ^ (((f >> 2) & 7) << 3);
                Zt[f][cs] = v[q];
            }
        }
        __syncthreads();
        for (int kk = 0; kk < 2; ++kk) {
            s16x8 a0 = *(const s16x8*)&Zt[ja0][(kk * 32 + lg * 8) ^ sa0];
            s16x8 a1 = *(const s16x8*)&Zt[ja1][(kk * 32 + lg * 8) ^ sa1];
            for (int nt = 0; nt < 16; ++nt) {
                int jb = nt * 16 + l15;
                int sb = ((jb >> 2) & 7) << 3;
                s16x8 b = *(const s16x8*)&Zt[jb][(kk * 32 + lg * 8) ^ sb];
                acc[0][nt] = __builtin_amdgcn_mfma_f32_16x16x32_bf16(a0, b, acc[0][nt], 0, 0, 0);
                acc[1][nt] = __builtin_amdgcn_mfma_f32_16x16x32_bf16(a1, b, acc[1][nt], 0, 0, 0);
            }
        }
    }
    for (int mt = 0; mt < 2; ++mt)
        for (int nt = 0; nt < 16; ++nt)
            for (int r = 0; r < 4; ++r)
                atomicAdd(&G[(wave * 32 + mt * 16 + lg * 4 + r) * 256 + nt * 16 + l15], acc[mt][nt][r]);
}

// ---------------- HM = l2norm(PA @ S) via MFMA; 128x256 tile, 2x4 waves ----------------
__global__ __launch_bounds__(512) void k_hm_mfma(const unsigned short* __restrict__ PA,
                                                 const unsigned short* __restrict__ St,
                                                 float* __restrict__ out, int M)
{
    __shared__ unsigned short Alds[128][72];
    __shared__ unsigned short Blds[256][72];
    __shared__ float part[4][136];
    const int tid = threadIdx.x;
    const int m0 = blockIdx.x * 128;
    const int wave = tid >> 6, lane = tid & 63;
    const int wr = wave >> 2, wc = wave & 3;
    const int l15 = lane & 15, lg = lane >> 4;

    f32x4 acc[4][4];
    for (int a = 0; a < 4; ++a) for (int b = 0; b < 4; ++b) acc[a][b] = (f32x4)0.0f;

    for (int k0 = 0; k0 < 256; k0 += 64) {
        for (int p = 0; p < 2; ++p) {
            int idx = tid + p * 512;          // 1024 u16x8 = 128 rows x 8
            int r = idx >> 3, k8 = idx & 7;
            int row = m0 + r;
            u16x8 v = (u16x8)0;
            if (row < M) v = *(const u16x8*)(PA + (size_t)row * 256 + k0 + k8 * 8);
            *(u16x8*)&Alds[r][k8 * 8] = v;
        }
        for (int p = 0; p < 4; ++p) {
            int idx = tid + p * 512;
            int j = idx >> 3, k8 = idx & 7;
            *(u16x8*)&Blds[j][k8 * 8] = *(const u16x8*)(St + (size_t)j * 256 + k8 * 8 + k0);
        }
        __syncthreads();
        for (int kk = 0; kk < 2; ++kk) {
            s16x8 af[4], bfr[4];
            for (int mt = 0; mt < 4; ++mt)
                af[mt] = *(const s16x8*)&Alds[wr * 64 + mt * 16 + l15][kk * 32 + lg * 8];
            for (int nt = 0; nt < 4; ++nt)
                bfr[nt] = *(const s16x8*)&Blds[wc * 64 + nt * 16 + l15][kk * 32 + lg * 8];
            for (int mt = 0; mt < 4; ++mt)
                for (int nt = 0; nt < 4; ++nt)
                    acc[mt][nt] = __builtin_amdgcn_mfma_f32_16x16x32_bf16(af[mt], bfr[nt], acc[mt][nt], 0, 0, 0);
        }
        __syncthreads();
    }

    for (int mt = 0; mt < 4; ++mt) {
        for (int r = 0; r < 4; ++r) {
            float p = 0.f;
            for (int nt = 0; nt < 4; ++nt) p += acc[mt][nt][r] * acc[mt][nt][r];
            p += __shfl_xor(p, 1); p += __shfl_xor(p, 2);
            p += __shfl_xor(p, 4); p += __shfl_xor(p, 8);
            if (l15 == 0) part[wc][wr * 64 + mt * 16 + lg * 4 + r] = p;
        }
    }
    __syncthreads();
    for (int mt = 0; mt < 4; ++mt) {
        for (int r = 0; r < 4; ++r) {
            int rl = wr * 64 + mt * 16 + lg * 4 + r;
            float s = part[0][rl] + part[1][rl] + part[2][rl] + part[3][rl];
            float inv = 1.0f / fmaxf(sqrtf(s), 1e-12f);
            int row = m0 + rl;
            if (row < M) {
                for (int nt = 0; nt < 4; ++nt)
                    out[(size_t)row * 256 + wc * 64 + nt * 16 + l15] = acc[mt][nt][r] * inv;
            }
        }
    }
}

// ---------------- fused softmax helpers (batched over both matrices) ----------------
__global__ __launch_bounds__(256) void k_max2(const float* __restrict__ G1, const float* __restrict__ G2,
                                              float* __restrict__ gmax)
{
    const float* G = blockIdx.x ? G2 : G1;
    float m = -1e30f;
    for (int i = threadIdx.x; i < 65536; i += 256) m = fmaxf(m, G[i]);
    for (int s = 1; s < 64; s <<= 1) m = fmaxf(m, __shfl_xor(m, s));
    __shared__ float wm[4];
    if ((threadIdx.x & 63) == 0) wm[threadIdx.x >> 6] = m;
    __syncthreads();
    if (threadIdx.x == 0) gmax[blockIdx.x] = fmaxf(fmaxf(wm[0], wm[1]), fmaxf(wm[2], wm[3]));
}

__global__ __launch_bounds__(256) void k_exprow(const float* __restrict__ G1, const float* __restrict__ G2,
                                                const float* __restrict__ gmax,
                                                float* __restrict__ E1, float* __restrict__ E2,
                                                float* __restrict__ rs)
{
    const float inv_sqrt_n = 4.4721359549995794e-3f;
    int i = blockIdx.x, z = blockIdx.y, j = threadIdx.x;
    const float* G = z ? G2 : G1;
    float* E = z ? E2 : E1;
    float e = expf((G[i * 256 + j] - gmax[z]) * inv_sqrt_n);
    E[i * 256 + j] = e;
    float v = e;
    for (int m = 1; m < 64; m <<= 1) v += __shfl_xor(v, m);
    __shared__ float wm[4];
    if ((j & 63) == 0) wm[j >> 6] = v;
    __syncthreads();
    if (j == 0) rs[z * 256 + i] = wm[0] + wm[1] + wm[2] + wm[3];
}

__global__ __launch_bounds__(256) void k_colsum(const float* __restrict__ E1, const float* __restrict__ E2,
                                                float* __restrict__ cs)
{
    int b = blockIdx.x, z = blockIdx.y, j = threadIdx.x;
    const float* E = z ? E2 : E1;
    float a = 0.f;
    for (int i = b * 32; i < b * 32 + 32; ++i) a += E[i * 256 + j];
    atomicAdd(&cs[z * 256 + j], a);
}

// SMh = 0.25*(...), S = SMh + I  (k_sinit fused)
__global__ __launch_bounds__(256) void k_smacc(const float* __restrict__ E1, const float* __restrict__ E2,
                                               const float* __restrict__ rs, const float* __restrict__ cs,
                                               float* __restrict__ SMh, float* __restrict__ S)
{
    int i = blockIdx.x, j = threadIdx.x;
    float v1 = E1[i * 256 + j] * rsqrtf(rs[i] + 1e-10f) * rsqrtf(cs[j] + 1e-10f);
    float v2 = E2[i * 256 + j] * rsqrtf(rs[256 + i] + 1e-10f) * rsqrtf(cs[256 + j] + 1e-10f);
    float v = 0.25f * (v1 + v2);
    SMh[i * 256 + j] = v;
    S[i * 256 + j] = v + (i == j ? 1.0f : 0.0f);
}

__global__ __launch_bounds__(256) void k_sgemm(const float* __restrict__ P, const float* __restrict__ SMh,
                                               float* __restrict__ Pn, float* __restrict__ S)
{
    __shared__ float pr[256];
    int i = blockIdx.x, j = threadIdx.x;
    pr[j] = P[i * 256 + j];
    __syncthreads();
    float a = 0.f;
    for (int k = 0; k < 256; ++k) a += pr[k] * SMh[k * 256 + j];
    Pn[i * 256 + j] = a;
    S[i * 256 + j] += a;
}

// ---------------- ZM: in-place average of the two bf16 copies ----------------
__global__ void k_zm(unsigned short* __restrict__ A, unsigned short* __restrict__ B)
{
    size_t i = ((size_t)blockIdx.x * 256 + threadIdx.x) * 8;
    u16x8 a = *(const u16x8*)(A + i), b = *(const u16x8*)(B + i);
    u16x8 c;
    for (int q = 0; q < 8; ++q) c[q] = f2bf(0.5f * (bf2f(a[q]) + bf2f(b[q])));
    *(u16x8*)(A + i) = c;
    *(u16x8*)(B + i) = c;
}

// ---------------- CSR build: hist + 3-phase parallel scan + scatter ----------------
__global__ void k_hist(const int* __restrict__ src, int* __restrict__ counts)
{
    int e = blockIdx.x * 256 + threadIdx.x;
    atomicAdd(&counts[src[e]], 1);
}

__global__ __launch_bounds__(256) void k_bsum(const int* __restrict__ counts, int* __restrict__ bsum)
{
    int i = blockIdx.x * 256 + threadIdx.x;
    int v = (i < N_NODES) ? counts[i] : 0;
    for (int m = 1; m < 64; m <<= 1) v += __shfl_xor(v, m);
    __shared__ int wm[4];
    if ((threadIdx.x & 63) == 0) wm[threadIdx.x >> 6] = v;
    __syncthreads();
    if (threadIdx.x == 0) bsum[blockIdx.x] = wm[0] + wm[1] + wm[2] + wm[3];
}

__global__ __launch_bounds__(256) void k_bscan(const int* __restrict__ bsum, int* __restrict__ boff,
                                               int* __restrict__ rowptr)
{
    __shared__ int tmp[256];
    int t = threadIdx.x;
    int v = (t < NBLK_SCAN) ? bsum[t] : 0;
    tmp[t] = v;
    __syncthreads();
    for (int off = 1; off < 256; off <<= 1) {
        int add = (t >= off) ? tmp[t - off] : 0;
        __syncthreads();
        tmp[t] += add;
        __syncthreads();
    }
    if (t < NBLK_SCAN) boff[t] = tmp[t] - v;
    if (t == NBLK_SCAN - 1) rowptr[N_NODES] = tmp[t];
}

__global__ __launch_bounds__(256) void k_rowptr(const int* __restrict__ counts, const int* __restrict__ boff,
                                                int* __restrict__ rowptr, int* __restrict__ cursor)
{
    __shared__ int tmp[256];
    int b = blockIdx.x, t = threadIdx.x;
    int i = b * 256 + t;
    int v = (i < N_NODES) ? counts[i] : 0;
    tmp[t] = v;
    __syncthreads();
    for (int off = 1; off < 256; off <<= 1) {
        int add = (t >= off) ? tmp[t - off] : 0;
        __syncthreads();
        tmp[t] += add;
        __syncthreads();
    }
    int excl = tmp[t] - v + boff[b];
    if (i < N_NODES) { rowptr[i] = excl; cursor[i] = excl; }
}

__global__ void k_scatter(const int* __restrict__ src, const int* __restrict__ dst,
                          const float* __restrict__ val, int* __restrict__ cursor,
                          int* __restrict__ sdst, float* __restrict__ sval)
{
    int e = blockIdx.x * 256 + threadIdx.x;
    int s = src[e];
    int pos = atomicAdd(&cursor[s], 1);
    sdst[pos] = dst[e];
    sval[pos] = val[e];
}

// ---------------- SpMM layer: wave-per-row, ushort4 gathers, unroll 8/4/1 ----------------
__global__ __launch_bounds__(256) void k_spmm(const int* __restrict__ rowptr, const int* __restrict__ sdst,
                                              const float* __restrict__ sval,
                                              const unsigned short* __restrict__ cur,
                                              unsigned short* __restrict__ nxt, unsigned short* __restrict__ PA)
{
    const int wave = threadIdx.x >> 6, lane = threadIdx.x & 63;
    const int r = blockIdx.x * 4 + wave;
    if (r >= N_NODES) return;
    const int lo = rowptr[r], hi = rowptr[r + 1];
    const unsigned short* curc = cur + lane * 4;

    float ax = 0.f, ay = 0.f, az = 0.f, aw = 0.f;
    float bx = 0.f, by = 0.f, bz = 0.f, bw = 0.f;
    float cx = 0.f, cy = 0.f, cz = 0.f, cw = 0.f;
    float dx = 0.f, dy = 0.f, dz = 0.f, dw = 0.f;
    int e = lo;
    for (; e + 8 <= hi; e += 8) {
        int   d0 = sdst[e],   d1 = sdst[e+1], d2 = sdst[e+2], d3 = sdst[e+3];
        int   d4 = sdst[e+4], d5 = sdst[e+5], d6 = sdst[e+6], d7 = sdst[e+7];
        float v0 = sval[e],   v1 = sval[e+1], v2 = sval[e+2], v3 = sval[e+3];
        float v4 = sval[e+4], v5 = sval[e+5], v6 = sval[e+6], v7 = sval[e+7];
        ushort4 g0 = *(const ushort4*)(curc + (size_t)d0 * 256);
        ushort4 g1 = *(const ushort4*)(curc + (size_t)d1 * 256);
        ushort4 g2 = *(const ushort4*)(curc + (size_t)d2 * 256);
        ushort4 g3 = *(const ushort4*)(curc + (size_t)d3 * 256);
        ushort4 g4 = *(const ushort4*)(curc + (size_t)d4 * 256);
        ushort4 g5 = *(const ushort4*)(curc + (size_t)d5 * 256);
        ushort4 g6 = *(const ushort4*)(curc + (size_t)d6 * 256);
        ushort4 g7 = *(const ushort4*)(curc + (size_t)d7 * 256);
        ax += v0 * bf2f(g0.x); ay += v0 * bf2f(g0.y); az += v0 * bf2f(g0.z); aw += v0 * bf2f(g0.w);
        bx += v1 * bf2f(g1.x); by += v1 * bf2f(g1.y); bz += v1 * bf2f(g1.z); bw += v1 * bf2f(g1.w);
        cx += v2 * bf2f(g2.x); cy += v2 * bf2f(g2.y); cz += v2 * bf2f(g2.z); cw += v2 * bf2f(g2.w);
        dx += v3 * bf2f(g3.x); dy += v3 * bf2f(g3.y); dz += v3 * bf2f(g3.z); dw += v3 * bf2f(g3.w);
        ax += v4 * bf2f(g4.x); ay += v4 * bf2f(g4.y); az += v4 * bf2f(g4.z); aw += v4 * bf2f(g4.w);
        bx += v5 * bf2f(g5.x); by += v5 * bf2f(g5.y); bz += v5 * bf2f(g5.z); bw += v5 * bf2f(g5.w);
        cx += v6 * bf2f(g6.x); cy += v6 * bf2f(g6.y); cz += v6 * bf2f(g6.z); cw += v6 * bf2f(g6.w);
        dx += v7 * bf2f(g7.x); dy += v7 * bf2f(g7.y); dz += v7 * bf2f(g7.z); dw += v7 * bf2f(g7.w);
    }
    if (e + 4 <= hi) {
        int   d0 = sdst[e],   d1 = sdst[e+1], d2 = sdst[e+2], d3 = sdst[e+3];
        float v0 = sval[e],   v1 = sval[e+1], v2 = sval[e+2], v3 = sval[e+3];
        ushort4 g0 = *(const ushort4*)(curc + (size_t)d0 * 256);
        ushort4 g1 = *(const ushort4*)(curc + (size_t)d1 * 256);
        ushort4 g2 = *(const ushort4*)(curc + (size_t)d2 * 256);
        ushort4 g3 = *(const ushort4*)(curc + (size_t)d3 * 256);
        ax += v0 * bf2f(g0.x); ay += v0 * bf2f(g0.y); az += v0 * bf2f(g0.z); aw += v0 * bf2f(g0.w);
        bx += v1 * bf2f(g1.x); by += v1 * bf2f(g1.y); bz += v1 * bf2f(g1.z); bw += v1 * bf2f(g1.w);
        cx += v2 * bf2f(g2.x); cy += v2 * bf2f(g2.y); cz += v2 * bf2f(g2.z); cw += v2 * bf2f(g2.w);
        dx += v3 * bf2f(g3.x); dy += v3 * bf2f(g3.y); dz += v3 * bf2f(g3.z); dw += v3 * bf2f(g3.w);
        e += 4;
    }
    for (; e < hi; ++e) {
        int d0 = sdst[e]; float v0 = sval[e];
        ushort4 g0 = *(const ushort4*)(curc + (size_t)d0 * 256);
        ax += v0 * bf2f(g0.x); ay += v0 * bf2f(g0.y); az += v0 * bf2f(g0.z); aw += v0 * bf2f(g0.w);
    }
    float vx = 0.5f * ((ax + bx) + (cx + dx));
    float vy = 0.5f * ((ay + by) + (cy + dy));
    float vz = 0.5f * ((az + bz) + (cz + dz));
    float vw = 0.5f * ((aw + bw) + (cw + dw));

    size_t idx = (size_t)r * 256 + lane * 4;
    ushort4 o; o.x = f2bf(vx); o.y = f2bf(vy); o.z = f2bf(vz); o.w = f2bf(vw);
    *(ushort4*)(nxt + idx) = o;
    ushort4 pa = *(const ushort4*)(PA + idx);
    ushort4 pn;
    pn.x = f2bf(bf2f(pa.x) + vx); pn.y = f2bf(bf2f(pa.y) + vy);
    pn.z = f2bf(bf2f(pa.z) + vz); pn.w = f2bf(bf2f(pa.w) + vw);
    *(ushort4*)(PA + idx) = pn;
}

// ---------------- diagnostic stamps ----------------
__global__ void k_stamp(float* __restrict__ out, float c0, float c1, float c2)
{
    if (c0 != 0.f) out[0] = c0;
    if (c1 != 0.f) out[1] = c1;
    if (c2 != 0.f) out[2] = c2;
}

extern "C" void kernel_launch(void* const* d_in, const int* in_sizes, int n_in,
                              void* d_out, int out_size, void* d_ws, size_t ws_size,
                              hipStream_t stream)
{
    const float* X1   = (const float*)d_in[0];
    const float* X2   = (const float*)d_in[1];
    const int*   esrc = (const int*)d_in[2];
    const int*   edst = (const int*)d_in[3];
    const float* eval = (const float*)d_in[4];
    const float* W1   = (const float*)d_in[5];
    const float* b1   = (const float*)d_in[6];
    const float* W2   = (const float*)d_in[7];
    const float* b2   = (const float*)d_in[8];

    float* out_zm1 = (float*)d_out;
    float* out_zm2 = out_zm1 + (size_t)N_NODES * 256;
    float* out_hm  = out_zm2 + (size_t)N_NODES * 256;

    // ---- workspace carve (~61.2 MB) ----
    char* w = (char*)d_ws;
    unsigned short* PAb   = (unsigned short*)w; w += 25600000;
    unsigned short* curA  = (unsigned short*)w; w += 25600000;
    int* sdst             = (int*)w;            w += 3200000;
    float* sval           = (float*)w;          w += 3200000;
    int* counts           = (int*)w;            w += 200192;
    int* rowptr           = (int*)w;            w += 200192;
    int* cursor           = (int*)w;            w += 200192;
    float* G1             = (float*)w;          w += 262144;
    float* G2             = (float*)w;          w += 262144;
    float* E1             = (float*)w;          w += 262144;
    float* E2             = (float*)w;          w += 262144;
    float* SMh            = (float*)w;          w += 262144;
    float* S              = (float*)w;          w += 262144;
    float* P2             = (float*)w;          w += 262144;
    float* P3             = (float*)w;          w += 262144;
    float* rs             = (float*)w;          w += 2048;
    float* cs             = (float*)w;          w += 2048;
    float* gmax           = (float*)w;          w += 256;
    int* bsum             = (int*)w;            w += 1024;
    int* boff             = (int*)w;            w += 1024;
    unsigned short* Wt1   = (unsigned short*)w; w += 393216;
    unsigned short* Wt2   = (unsigned short*)w; w += 262144;
    unsigned short* St    = (unsigned short*)w; w += 131072;
    size_t ws_need = (size_t)(w - (char*)d_ws);

    unsigned short* curB  = (unsigned short*)out_hm;   // dead until k_hm

    bool sizes_ok = (n_in == 9)
        && in_sizes[0] == 38400000 && in_sizes[1] == 25600000
        && in_sizes[2] == 800000 && in_sizes[3] == 800000 && in_sizes[4] == 800000
        && in_sizes[5] == 196608 && in_sizes[6] == 256
        && in_sizes[7] == 131072 && in_sizes[8] == 256;
    float c0 = (n_in != 9) ? 1000.f : 0.f;
    float c1 = (!sizes_ok && n_in == 9) ? 2000.f : 0.f;
    float c2 = (ws_size < ws_need) ? (4000.f + (float)(ws_size / 1000000ull)) : 0.f;

    // 0) weights -> bf16 transposed (single dispatch)
    k_wt2<<<1280, 256, 0, stream>>>(W1, W2, Wt1, Wt2);

    // 1) both GEMMs in one dispatch
    k_gemm2<<<dim3((N_NODES + 127) / 128, 1, 2), 512, 0, stream>>>(
        X1, X2, Wt1, Wt2, b1, b2, out_zm1, out_zm2, curA, PAb, N_NODES);

    // 2) Grams (single Z pass) + fused softmax chain
    hipMemsetAsync(G1, 0, 262144, stream);
    hipMemsetAsync(G2, 0, 262144, stream);
    hipMemsetAsync(cs, 0, 2048, stream);
    k_gram_mfma<<<dim3(196, 2), 512, 0, stream>>>(curA, PAb, G1, G2, N_NODES);
    k_max2<<<2, 256, 0, stream>>>(G1, G2, gmax);
    k_exprow<<<dim3(256, 2), 256, 0, stream>>>(G1, G2, gmax, E1, E2, rs);
    k_colsum<<<dim3(8, 2), 256, 0, stream>>>(E1, E2, cs);
    k_smacc<<<256, 256, 0, stream>>>(E1, E2, rs, cs, SMh, S);

    // 3) ZM: in-place average
    k_zm<<<6250, 256, 0, stream>>>(curA, PAb);

    // 4) CSR by src (parallel 3-phase scan)
    hipMemsetAsync(counts, 0, 200192, stream);
    k_hist<<<NE / 256, 256, 0, stream>>>(esrc, counts);
    k_bsum<<<NBLK_SCAN, 256, 0, stream>>>(counts, bsum);
    k_bscan<<<1, 256, 0, stream>>>(bsum, boff, rowptr);
    k_rowptr<<<NBLK_SCAN, 256, 0, stream>>>(counts, boff, rowptr, cursor);
    k_scatter<<<NE / 256, 256, 0, stream>>>(esrc, edst, eval, cursor, sdst, sval);

    // 5) 4 propagation layers, wave-per-row (unroll 8/4/1)
    k_spmm<<<12500, 256, 0, stream>>>(rowptr, sdst, sval, curA, curB, PAb);
    k_spmm<<<12500, 256, 0, stream>>>(rowptr, sdst, sval, curB, curA, PAb);
    k_spmm<<<12500, 256, 0, stream>>>(rowptr, sdst, sval, curA, curB, PAb);
    k_spmm<<<12500, 256, 0, stream>>>(rowptr, sdst, sval, curB, curA, PAb);

    // 6) S = I + B + B^2 + B^3 (S seeded by k_smacc), then St = bf16(S^T)
    k_sgemm<<<256, 256, 0, stream>>>(SMh, SMh, P2, S);
    k_sgemm<<<256, 256, 0, stream>>>(P2, SMh, P3, S);
    k_st<<<256, 256, 0, stream>>>(S, St);

    // 7) HM = l2norm(PA @ S)
    k_hm_mfma<<<(N_NODES + 127) / 128, 512, 0, stream>>>(PAb, St, out_hm, N_NODES);

    // 8) diagnostic stamps
    k_stamp<<<1, 1, 0, stream>>>(out_zm1, c0, c1, c2);
}

// Round 20
// 678.323 us; speedup vs baseline: 1.0537x; 1.0537x over previous
//
#include <hip/hip_runtime.h>
#include <hip/hip_bf16.h>

#define N_NODES 50000
#define NE      800000
#define NBLK_SCAN 196   // ceil(50000/256)

typedef __attribute__((ext_vector_type(4))) float f32x4;
typedef __attribute__((ext_vector_type(8))) short s16x8;
typedef __attribute__((ext_vector_type(8))) unsigned short u16x8;

__device__ __forceinline__ float bf2f(unsigned short u) {
    union { unsigned int i; float f; } v; v.i = ((unsigned int)u) << 16; return v.f;
}
__device__ __forceinline__ unsigned short f2bf(float f) {
    union { unsigned int i; float f; } v; v.f = f;
    unsigned int x = v.i;
    return (unsigned short)((x + 0x7fffu + ((x >> 16) & 1u)) >> 16);  // RNE
}

// ---------------- weights (both) -> bf16 transposed, one dispatch ----------------
__global__ void k_wt2(const float* __restrict__ W1, const float* __restrict__ W2,
                      unsigned short* __restrict__ Wt1, unsigned short* __restrict__ Wt2)
{
    int b = blockIdx.x;
    if (b < 768) {
        int idx = b * 256 + threadIdx.x;          // Wt1 flat = j*768 + k
        int j = idx / 768, k = idx - j * 768;
        Wt1[idx] = f2bf(W1[(size_t)k * 256 + j]);
    } else {
        int idx = (b - 768) * 256 + threadIdx.x;  // Wt2 flat = j*512 + k
        int j = idx >> 9, k = idx & 511;
        Wt2[idx] = f2bf(W2[(size_t)k * 256 + j]);
    }
}

// ---------------- S fp32 [256][256] -> St bf16 transposed ----------------
__global__ void k_st(const float* __restrict__ S, unsigned short* __restrict__ St)
{
    int k = blockIdx.x, j = threadIdx.x;
    St[j * 256 + k] = f2bf(S[k * 256 + j]);
}

// ---------------- both GEMMs in ONE dispatch; 128x256 tile, BK=64, 2x4 waves ----------------
__global__ __launch_bounds__(512) void k_gemm2(
    const float* __restrict__ X1, const float* __restrict__ X2,
    const unsigned short* __restrict__ Wt1, const unsigned short* __restrict__ Wt2,
    const float* __restrict__ b1f, const float* __restrict__ b2f,
    float* __restrict__ o1, float* __restrict__ o2,
    unsigned short* __restrict__ z1, unsigned short* __restrict__ z2, int M)
{
    __shared__ unsigned short Alds[128][72];
    __shared__ unsigned short Blds[256][72];
    __shared__ float part[4][136];
    const int zz = blockIdx.z;
    const float* X = zz ? X2 : X1;
    const unsigned short* Wt = zz ? Wt2 : Wt1;
    const float* bias = zz ? b2f : b1f;
    float* out = zz ? o2 : o1;
    unsigned short* Zb = zz ? z2 : z1;
    const int K = zz ? 512 : 768;

    const int tid = threadIdx.x;
    const int m0 = blockIdx.x * 128;
    const int wave = tid >> 6, lane = tid & 63;
    const int wr = wave >> 2, wc = wave & 3;
    const int l15 = lane & 15, lg = lane >> 4;

    f32x4 acc[4][4];
    for (int a = 0; a < 4; ++a) for (int b = 0; b < 4; ++b) acc[a][b] = (f32x4)0.0f;

    for (int k0 = 0; k0 < K; k0 += 64) {
        for (int p = 0; p < 4; ++p) {
            int idx = tid + p * 512;          // 2048 float4 = 128 rows x 16
            int r = idx >> 4, c4 = idx & 15;
            int row = m0 + r;
            float4 v = make_float4(0.f, 0.f, 0.f, 0.f);
            if (row < M) v = *(const float4*)(X + (size_t)row * K + k0 + c4 * 4);
            ushort4 pk;
            pk.x = f2bf(v.x); pk.y = f2bf(v.y); pk.z = f2bf(v.z); pk.w = f2bf(v.w);
            *(ushort4*)&Alds[r][c4 * 4] = pk;
        }
        for (int p = 0; p < 4; ++p) {
            int idx = tid + p * 512;          // 2048 u16x8
            int j = idx >> 3, k8 = idx & 7;
            *(u16x8*)&Blds[j][k8 * 8] = *(const u16x8*)(Wt + (size_t)j * K + k0 + k8 * 8);
        }
        __syncthreads();
        for (int kk = 0; kk < 2; ++kk) {
            s16x8 af[4], bfr[4];
            for (int mt = 0; mt < 4; ++mt)
                af[mt] = *(const s16x8*)&Alds[wr * 64 + mt * 16 + l15][kk * 32 + lg * 8];
            for (int nt = 0; nt < 4; ++nt)
                bfr[nt] = *(const s16x8*)&Blds[wc * 64 + nt * 16 + l15][kk * 32 + lg * 8];
            for (int mt = 0; mt < 4; ++mt)
                for (int nt = 0; nt < 4; ++nt)
                    acc[mt][nt] = __builtin_amdgcn_mfma_f32_16x16x32_bf16(af[mt], bfr[nt], acc[mt][nt], 0, 0, 0);
        }
        __syncthreads();
    }

    for (int mt = 0; mt < 4; ++mt) {
        for (int nt = 0; nt < 4; ++nt) {
            float bb = bias[wc * 64 + nt * 16 + l15];
            for (int r = 0; r < 4; ++r) acc[mt][nt][r] += bb;
        }
        for (int r = 0; r < 4; ++r) {
            float p = 0.f;
            for (int nt = 0; nt < 4; ++nt) p += acc[mt][nt][r] * acc[mt][nt][r];
            p += __shfl_xor(p, 1); p += __shfl_xor(p, 2);
            p += __shfl_xor(p, 4); p += __shfl_xor(p, 8);
            if (l15 == 0) part[wc][wr * 64 + mt * 16 + lg * 4 + r] = p;
        }
    }
    __syncthreads();
    for (int mt = 0; mt < 4; ++mt) {
        for (int r = 0; r < 4; ++r) {
            int rl = wr * 64 + mt * 16 + lg * 4 + r;
            float s = part[0][rl] + part[1][rl] + part[2][rl] + part[3][rl];
            float inv = 1.0f / fmaxf(sqrtf(s), 1e-12f);
            int row = m0 + rl;
            if (row < M) {
                for (int nt = 0; nt < 4; ++nt) {
                    float v = acc[mt][nt][r] * inv;
                    size_t o = (size_t)row * 256 + wc * 64 + nt * 16 + l15;
                    out[o] = v;
                    Zb[o] = f2bf(v);
                }
            }
        }
    }
}

// ---------------- Gram via MFMA: bf16 source, 128-row slabs, 16-chunk groups (R18 config) ----------------
__global__ __launch_bounds__(512) void k_gram_mfma(
    const unsigned short* __restrict__ Zb1, const unsigned short* __restrict__ Zb2,
    float* __restrict__ G1, float* __restrict__ G2, int M)
{
    __shared__ unsigned short Zt[256][72];
    const unsigned short* Z = blockIdx.z ? Zb2 : Zb1;
    float* G = blockIdx.z ? G2 : G1;
    const int tid = threadIdx.x;
    const int ib = blockIdx.x;
    const int wave = tid >> 6, lane = tid & 63;
    const int l15 = lane & 15, lg = lane >> 4;
    const int TC = (M + 63) >> 6;                 // 782
    const int c0 = blockIdx.y * 16;
    const int c1 = min(c0 + 16, TC);

    const int ja = ib * 128 + wave * 16 + l15;
    const int sa = ((ja >> 2) & 7) << 3;

    f32x4 acc[16];
    for (int i = 0; i < 16; ++i) acc[i] = (f32x4)0.0f;

    for (int ch = c0; ch < c1; ++ch) {
        int base = ch * 64;
        __syncthreads();
        for (int p = 0; p < 4; ++p) {
            int idx = tid + p * 512;              // 2048 u16x8 = 64 m x 32 c8
            int m = idx >> 5, c8 = idx & 31;
            int row = base + m;
            u16x8 v = (u16x8)0;
            if (row < M) v = *(const u16x8*)(Z + (size_t)row * 256 + c8 * 8);
            for (int q = 0; q < 8; ++q) {
                int f = c8 * 8 + q;
                int cs = m ^ (((f >> 2) & 7) << 3);
                Zt[f][cs] = v[q];
            }
        }
        __syncthreads();
        for (int kk = 0; kk < 2; ++kk) {
            s16x8 a = *(const s16x8*)&Zt[ja][(kk * 32 + lg * 8) ^ sa];
            for (int nt = 0; nt < 16; ++nt) {
                int jb = nt * 16 + l15;
                int sb = ((jb >> 2) & 7) << 3;
                s16x8 b = *(const s16x8*)&Zt[jb][(kk * 32 + lg * 8) ^ sb];
                acc[nt] = __builtin_amdgcn_mfma_f32_16x16x32_bf16(a, b, acc[nt], 0, 0, 0);
            }
        }
    }
    for (int nt = 0; nt < 16; ++nt)
        for (int r = 0; r < 4; ++r)
            atomicAdd(&G[(ib * 128 + wave * 16 + lg * 4 + r) * 256 + nt * 16 + l15], acc[nt][r]);
}

// ---------------- HM = l2norm(PA @ S) via MFMA; 128x256 tile, 2x4 waves ----------------
__global__ __launch_bounds__(512) void k_hm_mfma(const unsigned short* __restrict__ PA,
                                                 const unsigned short* __restrict__ St,
                                                 float* __restrict__ out, int M)
{
    __shared__ unsigned short Alds[128][72];
    __shared__ unsigned short Blds[256][72];
    __shared__ float part[4][136];
    const int tid = threadIdx.x;
    const int m0 = blockIdx.x * 128;
    const int wave = tid >> 6, lane = tid & 63;
    const int wr = wave >> 2, wc = wave & 3;
    const int l15 = lane & 15, lg = lane >> 4;

    f32x4 acc[4][4];
    for (int a = 0; a < 4; ++a) for (int b = 0; b < 4; ++b) acc[a][b] = (f32x4)0.0f;

    for (int k0 = 0; k0 < 256; k0 += 64) {
        for (int p = 0; p < 2; ++p) {
            int idx = tid + p * 512;          // 1024 u16x8 = 128 rows x 8
            int r = idx >> 3, k8 = idx & 7;
            int row = m0 + r;
            u16x8 v = (u16x8)0;
            if (row < M) v = *(const u16x8*)(PA + (size_t)row * 256 + k0 + k8 * 8);
            *(u16x8*)&Alds[r][k8 * 8] = v;
        }
        for (int p = 0; p < 4; ++p) {
            int idx = tid + p * 512;
            int j = idx >> 3, k8 = idx & 7;
            *(u16x8*)&Blds[j][k8 * 8] = *(const u16x8*)(St + (size_t)j * 256 + k8 * 8 + k0);
        }
        __syncthreads();
        for (int kk = 0; kk < 2; ++kk) {
            s16x8 af[4], bfr[4];
            for (int mt = 0; mt < 4; ++mt)
                af[mt] = *(const s16x8*)&Alds[wr * 64 + mt * 16 + l15][kk * 32 + lg * 8];
            for (int nt = 0; nt < 4; ++nt)
                bfr[nt] = *(const s16x8*)&Blds[wc * 64 + nt * 16 + l15][kk * 32 + lg * 8];
            for (int mt = 0; mt < 4; ++mt)
                for (int nt = 0; nt < 4; ++nt)
                    acc[mt][nt] = __builtin_amdgcn_mfma_f32_16x16x32_bf16(af[mt], bfr[nt], acc[mt][nt], 0, 0, 0);
        }
        __syncthreads();
    }

    for (int mt = 0; mt < 4; ++mt) {
        for (int r = 0; r < 4; ++r) {
            float p = 0.f;
            for (int nt = 0; nt < 4; ++nt) p += acc[mt][nt][r] * acc[mt][nt][r];
            p += __shfl_xor(p, 1); p += __shfl_xor(p, 2);
            p += __shfl_xor(p, 4); p += __shfl_xor(p, 8);
            if (l15 == 0) part[wc][wr * 64 + mt * 16 + lg * 4 + r] = p;
        }
    }
    __syncthreads();
    for (int mt = 0; mt < 4; ++mt) {
        for (int r = 0; r < 4; ++r) {
            int rl = wr * 64 + mt * 16 + lg * 4 + r;
            float s = part[0][rl] + part[1][rl] + part[2][rl] + part[3][rl];
            float inv = 1.0f / fmaxf(sqrtf(s), 1e-12f);
            int row = m0 + rl;
            if (row < M) {
                for (int nt = 0; nt < 4; ++nt)
                    out[(size_t)row * 256 + wc * 64 + nt * 16 + l15] = acc[mt][nt][r] * inv;
            }
        }
    }
}

// ---------------- fused softmax helpers (batched over both matrices) ----------------
__global__ __launch_bounds__(256) void k_max2(const float* __restrict__ G1, const float* __restrict__ G2,
                                              float* __restrict__ gmax)
{
    const float* G = blockIdx.x ? G2 : G1;
    float m = -1e30f;
    for (int i = threadIdx.x; i < 65536; i += 256) m = fmaxf(m, G[i]);
    for (int s = 1; s < 64; s <<= 1) m = fmaxf(m, __shfl_xor(m, s));
    __shared__ float wm[4];
    if ((threadIdx.x & 63) == 0) wm[threadIdx.x >> 6] = m;
    __syncthreads();
    if (threadIdx.x == 0) gmax[blockIdx.x] = fmaxf(fmaxf(wm[0], wm[1]), fmaxf(wm[2], wm[3]));
}

__global__ __launch_bounds__(256) void k_exprow(const float* __restrict__ G1, const float* __restrict__ G2,
                                                const float* __restrict__ gmax,
                                                float* __restrict__ E1, float* __restrict__ E2,
                                                float* __restrict__ rs)
{
    const float inv_sqrt_n = 4.4721359549995794e-3f;
    int i = blockIdx.x, z = blockIdx.y, j = threadIdx.x;
    const float* G = z ? G2 : G1;
    float* E = z ? E2 : E1;
    float e = expf((G[i * 256 + j] - gmax[z]) * inv_sqrt_n);
    E[i * 256 + j] = e;
    float v = e;
    for (int m = 1; m < 64; m <<= 1) v += __shfl_xor(v, m);
    __shared__ float wm[4];
    if ((j & 63) == 0) wm[j >> 6] = v;
    __syncthreads();
    if (j == 0) rs[z * 256 + i] = wm[0] + wm[1] + wm[2] + wm[3];
}

__global__ __launch_bounds__(256) void k_colsum(const float* __restrict__ E1, const float* __restrict__ E2,
                                                float* __restrict__ cs)
{
    int b = blockIdx.x, z = blockIdx.y, j = threadIdx.x;
    const float* E = z ? E2 : E1;
    float a = 0.f;
    for (int i = b * 32; i < b * 32 + 32; ++i) a += E[i * 256 + j];
    atomicAdd(&cs[z * 256 + j], a);
}

// SMh = 0.25*(...), S = SMh + I  (k_sinit fused)
__global__ __launch_bounds__(256) void k_smacc(const float* __restrict__ E1, const float* __restrict__ E2,
                                               const float* __restrict__ rs, const float* __restrict__ cs,
                                               float* __restrict__ SMh, float* __restrict__ S)
{
    int i = blockIdx.x, j = threadIdx.x;
    float v1 = E1[i * 256 + j] * rsqrtf(rs[i] + 1e-10f) * rsqrtf(cs[j] + 1e-10f);
    float v2 = E2[i * 256 + j] * rsqrtf(rs[256 + i] + 1e-10f) * rsqrtf(cs[256 + j] + 1e-10f);
    float v = 0.25f * (v1 + v2);
    SMh[i * 256 + j] = v;
    S[i * 256 + j] = v + (i == j ? 1.0f : 0.0f);
}

__global__ __launch_bounds__(256) void k_sgemm(const float* __restrict__ P, const float* __restrict__ SMh,
                                               float* __restrict__ Pn, float* __restrict__ S)
{
    __shared__ float pr[256];
    int i = blockIdx.x, j = threadIdx.x;
    pr[j] = P[i * 256 + j];
    __syncthreads();
    float a = 0.f;
    for (int k = 0; k < 256; ++k) a += pr[k] * SMh[k * 256 + j];
    Pn[i * 256 + j] = a;
    S[i * 256 + j] += a;
}

// ---------------- ZM: in-place average of the two bf16 copies ----------------
__global__ void k_zm(unsigned short* __restrict__ A, unsigned short* __restrict__ B)
{
    size_t i = ((size_t)blockIdx.x * 256 + threadIdx.x) * 8;
    u16x8 a = *(const u16x8*)(A + i), b = *(const u16x8*)(B + i);
    u16x8 c;
    for (int q = 0; q < 8; ++q) c[q] = f2bf(0.5f * (bf2f(a[q]) + bf2f(b[q])));
    *(u16x8*)(A + i) = c;
    *(u16x8*)(B + i) = c;
}

// ---------------- CSR build: hist + 3-phase parallel scan + scatter ----------------
__global__ void k_hist(const int* __restrict__ src, int* __restrict__ counts)
{
    int e = blockIdx.x * 256 + threadIdx.x;
    atomicAdd(&counts[src[e]], 1);
}

__global__ __launch_bounds__(256) void k_bsum(const int* __restrict__ counts, int* __restrict__ bsum)
{
    int i = blockIdx.x * 256 + threadIdx.x;
    int v = (i < N_NODES) ? counts[i] : 0;
    for (int m = 1; m < 64; m <<= 1) v += __shfl_xor(v, m);
    __shared__ int wm[4];
    if ((threadIdx.x & 63) == 0) wm[threadIdx.x >> 6] = v;
    __syncthreads();
    if (threadIdx.x == 0) bsum[blockIdx.x] = wm[0] + wm[1] + wm[2] + wm[3];
}

__global__ __launch_bounds__(256) void k_bscan(const int* __restrict__ bsum, int* __restrict__ boff,
                                               int* __restrict__ rowptr)
{
    __shared__ int tmp[256];
    int t = threadIdx.x;
    int v = (t < NBLK_SCAN) ? bsum[t] : 0;
    tmp[t] = v;
    __syncthreads();
    for (int off = 1; off < 256; off <<= 1) {
        int add = (t >= off) ? tmp[t - off] : 0;
        __syncthreads();
        tmp[t] += add;
        __syncthreads();
    }
    if (t < NBLK_SCAN) boff[t] = tmp[t] - v;
    if (t == NBLK_SCAN - 1) rowptr[N_NODES] = tmp[t];
}

__global__ __launch_bounds__(256) void k_rowptr(const int* __restrict__ counts, const int* __restrict__ boff,
                                                int* __restrict__ rowptr, int* __restrict__ cursor)
{
    __shared__ int tmp[256];
    int b = blockIdx.x, t = threadIdx.x;
    int i = b * 256 + t;
    int v = (i < N_NODES) ? counts[i] : 0;
    tmp[t] = v;
    __syncthreads();
    for (int off = 1; off < 256; off <<= 1) {
        int add = (t >= off) ? tmp[t - off] : 0;
        __syncthreads();
        tmp[t] += add;
        __syncthreads();
    }
    int excl = tmp[t] - v + boff[b];
    if (i < N_NODES) { rowptr[i] = excl; cursor[i] = excl; }
}

__global__ void k_scatter(const int* __restrict__ src, const int* __restrict__ dst,
                          const float* __restrict__ val, int* __restrict__ cursor,
                          int* __restrict__ sdst, float* __restrict__ sval)
{
    int e = blockIdx.x * 256 + threadIdx.x;
    int s = src[e];
    int pos = atomicAdd(&cursor[s], 1);
    sdst[pos] = dst[e];
    sval[pos] = val[e];
}

// ---------------- SpMM layer: wave-per-row, ushort4 gathers, unroll-4 (R18 config) ----------------
__global__ __launch_bounds__(256) void k_spmm(const int* __restrict__ rowptr, const int* __restrict__ sdst,
                                              const float* __restrict__ sval,
                                              const unsigned short* __restrict__ cur,
                                              unsigned short* __restrict__ nxt, unsigned short* __restrict__ PA)
{
    const int wave = threadIdx.x >> 6, lane = threadIdx.x & 63;
    const int r = blockIdx.x * 4 + wave;
    if (r >= N_NODES) return;
    const int lo = rowptr[r], hi = rowptr[r + 1];
    const int c0 = lane * 4;

    float ax = 0.f, ay = 0.f, az = 0.f, aw = 0.f;
    float bx = 0.f, by = 0.f, bz = 0.f, bw = 0.f;
    float cx = 0.f, cy = 0.f, cz = 0.f, cw = 0.f;
    float dx = 0.f, dy = 0.f, dz = 0.f, dw = 0.f;
    int e = lo;
    for (; e + 4 <= hi; e += 4) {
        int   d0 = sdst[e],     d1 = sdst[e + 1], d2 = sdst[e + 2], d3 = sdst[e + 3];
        float v0 = sval[e],     v1 = sval[e + 1], v2 = sval[e + 2], v3 = sval[e + 3];
        ushort4 g0 = *(const ushort4*)(cur + (size_t)d0 * 256 + c0);
        ushort4 g1 = *(const ushort4*)(cur + (size_t)d1 * 256 + c0);
        ushort4 g2 = *(const ushort4*)(cur + (size_t)d2 * 256 + c0);
        ushort4 g3 = *(const ushort4*)(cur + (size_t)d3 * 256 + c0);
        ax += v0 * bf2f(g0.x); ay += v0 * bf2f(g0.y); az += v0 * bf2f(g0.z); aw += v0 * bf2f(g0.w);
        bx += v1 * bf2f(g1.x); by += v1 * bf2f(g1.y); bz += v1 * bf2f(g1.z); bw += v1 * bf2f(g1.w);
        cx += v2 * bf2f(g2.x); cy += v2 * bf2f(g2.y); cz += v2 * bf2f(g2.z); cw += v2 * bf2f(g2.w);
        dx += v3 * bf2f(g3.x); dy += v3 * bf2f(g3.y); dz += v3 * bf2f(g3.z); dw += v3 * bf2f(g3.w);
    }
    for (; e < hi; ++e) {
        int d0 = sdst[e]; float v0 = sval[e];
        ushort4 g0 = *(const ushort4*)(cur + (size_t)d0 * 256 + c0);
        ax += v0 * bf2f(g0.x); ay += v0 * bf2f(g0.y); az += v0 * bf2f(g0.z); aw += v0 * bf2f(g0.w);
    }
    float vx = 0.5f * ((ax + bx) + (cx + dx));
    float vy = 0.5f * ((ay + by) + (cy + dy));
    float vz = 0.5f * ((az + bz) + (cz + dz));
    float vw = 0.5f * ((aw + bw) + (cw + dw));

    size_t idx = (size_t)r * 256 + c0;
    ushort4 o; o.x = f2bf(vx); o.y = f2bf(vy); o.z = f2bf(vz); o.w = f2bf(vw);
    *(ushort4*)(nxt + idx) = o;
    ushort4 pa = *(const ushort4*)(PA + idx);
    ushort4 pn;
    pn.x = f2bf(bf2f(pa.x) + vx); pn.y = f2bf(bf2f(pa.y) + vy);
    pn.z = f2bf(bf2f(pa.z) + vz); pn.w = f2bf(bf2f(pa.w) + vw);
    *(ushort4*)(PA + idx) = pn;
}

// ---------------- diagnostic stamps ----------------
__global__ void k_stamp(float* __restrict__ out, float c0, float c1, float c2)
{
    if (c0 != 0.f) out[0] = c0;
    if (c1 != 0.f) out[1] = c1;
    if (c2 != 0.f) out[2] = c2;
}

extern "C" void kernel_launch(void* const* d_in, const int* in_sizes, int n_in,
                              void* d_out, int out_size, void* d_ws, size_t ws_size,
                              hipStream_t stream)
{
    const float* X1   = (const float*)d_in[0];
    const float* X2   = (const float*)d_in[1];
    const int*   esrc = (const int*)d_in[2];
    const int*   edst = (const int*)d_in[3];
    const float* eval = (const float*)d_in[4];
    const float* W1   = (const float*)d_in[5];
    const float* b1   = (const float*)d_in[6];
    const float* W2   = (const float*)d_in[7];
    const float* b2   = (const float*)d_in[8];

    float* out_zm1 = (float*)d_out;
    float* out_zm2 = out_zm1 + (size_t)N_NODES * 256;
    float* out_hm  = out_zm2 + (size_t)N_NODES * 256;

    // ---- workspace carve (~61.2 MB) ----
    char* w = (char*)d_ws;
    unsigned short* PAb   = (unsigned short*)w; w += 25600000;
    unsigned short* curA  = (unsigned short*)w; w += 25600000;
    int* sdst             = (int*)w;            w += 3200000;
    float* sval           = (float*)w;          w += 3200000;
    int* counts           = (int*)w;            w += 200192;
    int* rowptr           = (int*)w;            w += 200192;
    int* cursor           = (int*)w;            w += 200192;
    float* G1             = (float*)w;          w += 262144;
    float* G2             = (float*)w;          w += 262144;
    float* E1             = (float*)w;          w += 262144;
    float* E2             = (float*)w;          w += 262144;
    float* SMh            = (float*)w;          w += 262144;
    float* S              = (float*)w;          w += 262144;
    float* P2             = (float*)w;          w += 262144;
    float* P3             = (float*)w;          w += 262144;
    float* rs             = (float*)w;          w += 2048;
    float* cs             = (float*)w;          w += 2048;
    float* gmax           = (float*)w;          w += 256;
    int* bsum             = (int*)w;            w += 1024;
    int* boff             = (int*)w;            w += 1024;
    unsigned short* Wt1   = (unsigned short*)w; w += 393216;
    unsigned short* Wt2   = (unsigned short*)w; w += 262144;
    unsigned short* St    = (unsigned short*)w; w += 131072;
    size_t ws_need = (size_t)(w - (char*)d_ws);

    unsigned short* curB  = (unsigned short*)out_hm;   // dead until k_hm

    bool sizes_ok = (n_in == 9)
        && in_sizes[0] == 38400000 && in_sizes[1] == 25600000
        && in_sizes[2] == 800000 && in_sizes[3] == 800000 && in_sizes[4] == 800000
        && in_sizes[5] == 196608 && in_sizes[6] == 256
        && in_sizes[7] == 131072 && in_sizes[8] == 256;
    float c0 = (n_in != 9) ? 1000.f : 0.f;
    float c1 = (!sizes_ok && n_in == 9) ? 2000.f : 0.f;
    float c2 = (ws_size < ws_need) ? (4000.f + (float)(ws_size / 1000000ull)) : 0.f;

    // 0) weights -> bf16 transposed (single dispatch)
    k_wt2<<<1280, 256, 0, stream>>>(W1, W2, Wt1, Wt2);

    // 1) both GEMMs in one dispatch
    k_gemm2<<<dim3((N_NODES + 127) / 128, 1, 2), 512, 0, stream>>>(
        X1, X2, Wt1, Wt2, b1, b2, out_zm1, out_zm2, curA, PAb, N_NODES);

    // 2) Grams (R18 16-chunk split) + fused softmax chain
    hipMemsetAsync(G1, 0, 262144, stream);
    hipMemsetAsync(G2, 0, 262144, stream);
    hipMemsetAsync(cs, 0, 2048, stream);
    k_gram_mfma<<<dim3(2, 49, 2), 512, 0, stream>>>(curA, PAb, G1, G2, N_NODES);
    k_max2<<<2, 256, 0, stream>>>(G1, G2, gmax);
    k_exprow<<<dim3(256, 2), 256, 0, stream>>>(G1, G2, gmax, E1, E2, rs);
    k_colsum<<<dim3(8, 2), 256, 0, stream>>>(E1, E2, cs);
    k_smacc<<<256, 256, 0, stream>>>(E1, E2, rs, cs, SMh, S);

    // 3) ZM: in-place average
    k_zm<<<6250, 256, 0, stream>>>(curA, PAb);

    // 4) CSR by src (parallel 3-phase scan)
    hipMemsetAsync(counts, 0, 200192, stream);
    k_hist<<<NE / 256, 256, 0, stream>>>(esrc, counts);
    k_bsum<<<NBLK_SCAN, 256, 0, stream>>>(counts, bsum);
    k_bscan<<<1, 256, 0, stream>>>(bsum, boff, rowptr);
    k_rowptr<<<NBLK_SCAN, 256, 0, stream>>>(counts, boff, rowptr, cursor);
    k_scatter<<<NE / 256, 256, 0, stream>>>(esrc, edst, eval, cursor, sdst, sval);

    // 5) 4 propagation layers, wave-per-row (unroll-4)
    k_spmm<<<12500, 256, 0, stream>>>(rowptr, sdst, sval, curA, curB, PAb);
    k_spmm<<<12500, 256, 0, stream>>>(rowptr, sdst, sval, curB, curA, PAb);
    k_spmm<<<12500, 256, 0, stream>>>(rowptr, sdst, sval, curA, curB, PAb);
    k_spmm<<<12500, 256, 0, stream>>>(rowptr, sdst, sval, curB, curA, PAb);

    // 6) S = I + B + B^2 + B^3 (S seeded by k_smacc), then St = bf16(S^T)
    k_sgemm<<<256, 256, 0, stream>>>(SMh, SMh, P2, S);
    k_sgemm<<<256, 256, 0, stream>>>(P2, SMh, P3, S);
    k_st<<<256, 256, 0, stream>>>(S, St);

    // 7) HM = l2norm(PA @ S)
    k_hm_mfma<<<(N_NODES + 127) / 128, 512, 0, stream>>>(PAb, St, out_hm, N_NODES);

    // 8) diagnostic stamps
    k_stamp<<<1, 1, 0, stream>>>(out_zm1, c0, c1, c2);
}